// Round 1
// baseline (119.554 us; speedup 1.0000x reference)
//
#include <hip/hip_runtime.h>
#include <cstdint>
#include <cstddef>

typedef __attribute__((ext_vector_type(4))) float f32x4;
typedef __attribute__((ext_vector_type(8))) short bf16x8;
typedef __attribute__((ext_vector_type(4))) short bf16x4;
typedef __attribute__((ext_vector_type(2))) short bf16x2;

#define DEVI static __device__ __forceinline__

DEVI short f2bf(float f){
  union { float f; uint32_t u; } v; v.f = f;
  uint32_t r = v.u + 0x7FFFu + ((v.u >> 16) & 1u);
  return (short)(r >> 16);
}
DEVI float bf2f(short h){
  union { uint32_t u; float f; } v; v.u = ((uint32_t)(uint16_t)h) << 16;
  return v.f;
}
DEVI float eluf(float x){ return x > 0.f ? x : (__expf(x) - 1.f); }
DEVI float sigm(float x){ return 1.f / (1.f + __expf(-x)); }

static constexpr int NPIX = 8 * 1024;   // B*S pixels

// ---- workspace layout (bytes), total ~58 MB ----
static constexpr size_t SZ_W   = (size_t)983040 * 2;        // 3 branches x (w1 65536 + w2 131072 + wn 131072) bf16
static constexpr size_t SZ_ACT = (size_t)NPIX * 256 * 2;    // 4 MiB bf16 activation
static constexpr size_t SZ_TOK = (size_t)NPIX * 512 * 2;    // 8 MiB bf16
static constexpr size_t OFF_W   = 0;
static constexpr size_t OFF_EXQ = OFF_W + SZ_W;
static constexpr size_t OFF_EXK = OFF_EXQ + SZ_ACT;
static constexpr size_t OFF_H1  = OFF_EXK + SZ_ACT;         // x3 branches
static constexpr size_t OFF_GR  = OFF_H1 + 3*SZ_ACT;        // x3 branches
static constexpr size_t OFF_TOK = OFF_GR + 3*SZ_ACT;        // x3 branches (channel-major bf16)

// ---------------- weight fp32 -> bf16 ----------------
__global__ void k_prep(const float* __restrict__ w1q, const float* __restrict__ w2q, const float* __restrict__ wnq,
                       const float* __restrict__ w1k, const float* __restrict__ w2k, const float* __restrict__ wnk,
                       const float* __restrict__ w1v, const float* __restrict__ w2v, const float* __restrict__ wnv,
                       short* __restrict__ dst)
{
  const float* s1[3] = {w1q, w1k, w1v};
  const float* s2[3] = {w2q, w2k, w2v};
  const float* s3[3] = {wnq, wnk, wnv};
  const int stride = gridDim.x * blockDim.x;
  for (int i = blockIdx.x * blockDim.x + threadIdx.x; i < 983040; i += stride){
    int br = i / 327680;
    int r  = i - br * 327680;
    float v;
    if (r < 65536)        v = s1[br][r];
    else if (r < 196608)  v = s2[br][r - 65536];
    else                  v = s3[br][r - 196608];
    dst[i] = f2bf(v);
  }
}

// ------------- elu + transpose to token-major bf16 -------------
// in: (B,256,1024) fp32 channel-major; out: (B*S, 256) bf16 token-major
__global__ void k_elutr(const float* __restrict__ qin, const float* __restrict__ kin,
                        short* __restrict__ exq, short* __restrict__ exk)
{
  const int z = blockIdx.z;
  const int which = z >> 3, b = z & 7;
  const float* x = which ? kin : qin;
  short* dst = which ? exk : exq;
  const int c0 = blockIdx.y * 64, s0 = blockIdx.x * 64;
  __shared__ short t[64][65];
  const int tid = threadIdx.x;
  for (int i = tid; i < 64*64; i += 256){
    int c = i >> 6, s = i & 63;
    float v = x[((size_t)b*256 + c0 + c)*1024 + s0 + s];
    t[s][c] = f2bf(eluf(v));
  }
  __syncthreads();
  for (int i = tid; i < 64*64; i += 256){
    int s = i >> 6, c = i & 63;
    dst[((size_t)(b*1024 + s0 + s))*256 + c0 + c] = t[s][c];
  }
}

// ---------------- GEMM core ----------------
// C tile = W[m0 .. m0+NA*64 rows (second 64 at +256)] @ act^T, cols nbase..nbase+127
// W row-major [M][256] bf16; act token-major [NPIX][256] bf16.
template<int NA>
DEVI void gemm_core(const short* __restrict__ Wt, const short* __restrict__ act,
                    int m0, int nbase, short* ldsA, short* ldsB,
                    f32x4 (&acc)[NA][4][2])
{
  const int tid = threadIdx.x;
  const int w = tid >> 6, g = (tid >> 4) & 3, li = tid & 15;
  for (int kb = 0; kb < 256; kb += 64){
    __syncthreads();
    #pragma unroll
    for (int it = 0; it < NA*2; it++){
      int i = tid + it*256;
      int m = i >> 3, kc = i & 7;
      int mr = (m & 63) + ((m >> 6) << 8);   // second A-tile rows at +256
      bf16x8 v = *(const bf16x8*)(Wt + (size_t)(m0 + mr)*256 + kb + kc*8);
      *(bf16x8*)(ldsA + ((m*64 + kc*8) ^ ((m & 7) << 3))) = v;
    }
    #pragma unroll
    for (int it = 0; it < 4; it++){
      int i = tid + it*256;
      int n = i >> 3, kc = i & 7;
      bf16x8 v = *(const bf16x8*)(act + (size_t)(nbase + n)*256 + kb + kc*8);
      *(bf16x8*)(ldsB + ((n*64 + kc*8) ^ ((n & 7) << 3))) = v;
    }
    __syncthreads();
    #pragma unroll
    for (int kk = 0; kk < 2; kk++){
      bf16x8 bfr[2];
      #pragma unroll
      for (int nt = 0; nt < 2; nt++){
        int n = w*32 + nt*16 + li;
        bfr[nt] = *(const bf16x8*)(ldsB + ((n*64 + kk*32 + g*8) ^ ((n & 7) << 3)));
      }
      #pragma unroll
      for (int a = 0; a < NA; a++){
        #pragma unroll
        for (int mt = 0; mt < 4; mt++){
          int m = a*64 + mt*16 + li;
          bf16x8 afr = *(const bf16x8*)(ldsA + ((m*64 + kk*32 + g*8) ^ ((m & 7) << 3)));
          #pragma unroll
          for (int nt = 0; nt < 2; nt++)
            acc[a][mt][nt] = __builtin_amdgcn_mfma_f32_16x16x32_bf16(afr, bfr[nt], acc[a][mt][nt], 0, 0, 0);
        }
      }
    }
  }
}

// gemm1: H1e = elu(W1 @ Ex + b1), token-major bf16 out
__global__ void k_gemm1(const short* __restrict__ wsW,
                        const short* __restrict__ exq, const short* __restrict__ exk,
                        const float* __restrict__ bq, const float* __restrict__ bk, const float* __restrict__ bv,
                        short* __restrict__ h1)
{
  __shared__ short ldsA[64*64];
  __shared__ short ldsB[128*64];
  const int z = blockIdx.z;
  const short* Wt  = wsW + (size_t)z * 327680;
  const short* act = (z == 0) ? exq : exk;
  const float* bias = (z == 0) ? bq : ((z == 1) ? bk : bv);
  short* out = h1 + (size_t)z * NPIX * 256;
  const int m0 = blockIdx.x * 64, nbase = blockIdx.y * 128;
  f32x4 acc[1][4][2] = {};
  gemm_core<1>(Wt, act, m0, nbase, ldsA, ldsB, acc);
  const int tid = threadIdx.x, w = tid >> 6, g = (tid >> 4) & 3, li = tid & 15;
  #pragma unroll
  for (int mt = 0; mt < 4; mt++){
    const int mb = m0 + mt*16 + g*4;
    #pragma unroll
    for (int nt = 0; nt < 2; nt++){
      const int n = nbase + w*32 + nt*16 + li;
      bf16x4 pk;
      #pragma unroll
      for (int r = 0; r < 4; r++)
        pk[r] = f2bf(eluf(acc[0][mt][nt][r] + bias[mb + r]));
      *(bf16x4*)(out + (size_t)n*256 + mb) = pk;
    }
  }
}

// gemm2: [a;g] = W2 @ H1e + b2 ; GR = X + a*sigmoid(g), token-major bf16 out
__global__ void k_gemm2(const short* __restrict__ wsW, const short* __restrict__ h1,
                        const float* __restrict__ bq, const float* __restrict__ bk, const float* __restrict__ bv,
                        const float* __restrict__ xq, const float* __restrict__ xk,
                        short* __restrict__ grb)
{
  __shared__ short ldsA[128*64];
  __shared__ short ldsB[128*64];
  const int z = blockIdx.z;
  const short* Wt  = wsW + (size_t)z * 327680 + 65536;
  const short* act = h1 + (size_t)z * NPIX * 256;
  const float* bias = (z == 0) ? bq : ((z == 1) ? bk : bv);
  const float* X = (z == 0) ? xq : xk;
  short* out = grb + (size_t)z * NPIX * 256;
  const int m0 = blockIdx.x * 64, nbase = blockIdx.y * 128;
  f32x4 acc[2][4][2] = {};
  gemm_core<2>(Wt, act, m0, nbase, ldsA, ldsB, acc);
  const int tid = threadIdx.x, w = tid >> 6, g = (tid >> 4) & 3, li = tid & 15;
  #pragma unroll
  for (int mt = 0; mt < 4; mt++){
    const int mb = m0 + mt*16 + g*4;
    #pragma unroll
    for (int nt = 0; nt < 2; nt++){
      const int n = nbase + w*32 + nt*16 + li;
      const int bidx = n >> 10, sp = n & 1023;
      bf16x4 pk;
      #pragma unroll
      for (int r = 0; r < 4; r++){
        const int m = mb + r;
        float a  = acc[0][mt][nt][r] + bias[m];
        float gg = acc[1][mt][nt][r] + bias[m + 256];
        float xv = X[((size_t)bidx*256 + m)*1024 + sp];
        pk[r] = f2bf(xv + a * sigm(gg));
      }
      *(bf16x4*)(out + (size_t)n*256 + mb) = pk;
    }
  }
}

// gemm3: tok = Wn @ GR + bn, stored CHANNEL-major (B,512,1024) bf16 (= attention token rows)
__global__ void k_gemm3(const short* __restrict__ wsW, const short* __restrict__ grb,
                        const float* __restrict__ bq, const float* __restrict__ bk, const float* __restrict__ bv,
                        short* __restrict__ tok)
{
  __shared__ short ldsA[64*64];
  __shared__ short ldsB[128*64];
  const int z = blockIdx.z;
  const short* Wt  = wsW + (size_t)z * 327680 + 196608;
  const short* act = grb + (size_t)z * NPIX * 256;
  const float* bias = (z == 0) ? bq : ((z == 1) ? bk : bv);
  short* out = tok + (size_t)z * NPIX * 512;
  const int m0 = blockIdx.x * 64, nbase = blockIdx.y * 128;
  f32x4 acc[1][4][2] = {};
  gemm_core<1>(Wt, act, m0, nbase, ldsA, ldsB, acc);
  const int tid = threadIdx.x, w = tid >> 6, g = (tid >> 4) & 3, li = tid & 15;
  #pragma unroll
  for (int mt = 0; mt < 4; mt++){
    #pragma unroll
    for (int nt = 0; nt < 2; nt++){
      const int n = nbase + w*32 + nt*16 + li;
      const int bidx = n >> 10, sp = n & 1023;
      #pragma unroll
      for (int r = 0; r < 4; r++){
        const int m = m0 + mt*16 + g*4 + r;
        out[((size_t)bidx*512 + m)*1024 + sp] = f2bf(acc[0][mt][nt][r] + bias[m]);
      }
    }
  }
}

// ---------------- flash attention ----------------
// tok viewed as (B*1024 tokens, 512 feat) bf16; per (b, head): Q,K,V (1024 x 64).
// Strict causal (key < query), scale 1/sqrt(512), row 0 -> 0.
// Swapped QK^T: S^T = mfma(K, Q^T) so softmax state is lane-local (lane owns q = lane&15).
__global__ void k_attn(const short* __restrict__ tok, float* __restrict__ out)
{
  const short* qtok = tok;
  const short* ktok = tok + (size_t)NPIX * 512;
  const short* vtok = tok + (size_t)2 * NPIX * 512;
  const int qt = blockIdx.x, nh = blockIdx.y, b = blockIdx.z;
  const int tid = threadIdx.x, lane = tid & 63, w = tid >> 6, g = (tid >> 4) & 3, li = tid & 15;
  const int qbase = qt * 64;
  const int qrow = qbase + w*16 + li;       // this lane's query token
  __shared__ short Kl[64*64];
  __shared__ short Vt[64*64];               // V transposed: [d][k]
  __shared__ short Pl[4][1024];             // per-wave P [16 q][64 k]

  const short* qptr = qtok + ((size_t)(b*1024 + qrow))*512 + nh*64;
  bf16x8 qf0 = *(const bf16x8*)(qptr + g*8);
  bf16x8 qf1 = *(const bf16x8*)(qptr + 32 + g*8);

  f32x4 accO[4] = {};                       // O^T: 4 d-frags x (16d x 16q)
  float mrun = -1e30f, lrun = 0.f;
  const float scale = 0.04419417382415922f; // 1/sqrt(512)
  short* Pw = &Pl[w][0];

  for (int kt = 0; kt <= qt; kt++){
    const int kb = kt * 64;
    __syncthreads();
    #pragma unroll
    for (int it = 0; it < 2; it++){
      int i = tid + it*256;
      int kr = i >> 3, kc = i & 7;
      bf16x8 v = *(const bf16x8*)(ktok + ((size_t)(b*1024 + kb + kr))*512 + nh*64 + kc*8);
      *(bf16x8*)(Kl + ((kr*64 + kc*8) ^ ((kr & 7) << 3))) = v;
    }
    #pragma unroll
    for (int it = 0; it < 2; it++){
      int d0 = w*8 + it*32;                 // d uniform within wave -> conflict-free writes
      bf16x8 v = *(const bf16x8*)(vtok + ((size_t)(b*1024 + kb + lane))*512 + nh*64 + d0);
      #pragma unroll
      for (int j = 0; j < 8; j++){
        int d = d0 + j;
        Vt[(d*64 + lane) ^ ((d & 7) << 3)] = v[j];
      }
    }
    __syncthreads();

    // S^T frags: 4 x (16 keys x 16 q)
    float pv[16];
    float mt_ = -1e30f;
    const bool diag = (kt == qt);
    #pragma unroll
    for (int kf = 0; kf < 4; kf++){
      f32x4 sa = {};
      const int krow = kf*16 + li;
      bf16x8 ka = *(const bf16x8*)(Kl + ((krow*64 + g*8) ^ ((krow & 7) << 3)));
      bf16x8 kbf = *(const bf16x8*)(Kl + ((krow*64 + 32 + g*8) ^ ((krow & 7) << 3)));
      sa = __builtin_amdgcn_mfma_f32_16x16x32_bf16(ka, qf0, sa, 0, 0, 0);
      sa = __builtin_amdgcn_mfma_f32_16x16x32_bf16(kbf, qf1, sa, 0, 0, 0);
      #pragma unroll
      for (int r = 0; r < 4; r++){
        const int keyg = kb + kf*16 + g*4 + r;
        float s = sa[r] * scale;
        const bool ok = (!diag) || (keyg < qrow);   // strict causal
        s = ok ? s : -1e30f;
        pv[kf*4 + r] = s;
        mt_ = fmaxf(mt_, s);
      }
    }
    mt_ = fmaxf(mt_, __shfl_xor(mt_, 16));
    mt_ = fmaxf(mt_, __shfl_xor(mt_, 32));
    const float mnew = fmaxf(mrun, mt_);
    const float alpha = __expf(mrun - mnew);
    short pr[16];
    float rs = 0.f;
    #pragma unroll
    for (int i2 = 0; i2 < 16; i2++){
      float p = (pv[i2] > -9e29f) ? __expf(pv[i2] - mnew) : 0.f;
      short pb = f2bf(p);
      pr[i2] = pb;
      rs += bf2f(pb);            // denominator from rounded P (consistent with numerator)
    }
    rs += __shfl_xor(rs, 16);
    rs += __shfl_xor(rs, 32);
    lrun = lrun * alpha + rs;
    mrun = mnew;
    #pragma unroll
    for (int df = 0; df < 4; df++){
      accO[df][0] *= alpha; accO[df][1] *= alpha;
      accO[df][2] *= alpha; accO[df][3] *= alpha;
    }
    // P rows to per-wave LDS (b32 packed pairs; keys 4g+2rp consecutive)
    #pragma unroll
    for (int kf = 0; kf < 4; kf++){
      #pragma unroll
      for (int rp = 0; rp < 2; rp++){
        bf16x2 two;
        two[0] = pr[kf*4 + rp*2];
        two[1] = pr[kf*4 + rp*2 + 1];
        const int key = kf*16 + g*4 + rp*2;
        *(bf16x2*)(Pw + ((li*64 + key) ^ ((li & 7) << 3))) = two;
      }
    }
    // O^T += V^T @ P^T
    #pragma unroll
    for (int kc = 0; kc < 2; kc++){
      bf16x8 pf = *(const bf16x8*)(Pw + ((li*64 + kc*32 + g*8) ^ ((li & 7) << 3)));
      #pragma unroll
      for (int df = 0; df < 4; df++){
        const int dr = df*16 + li;
        bf16x8 vf = *(const bf16x8*)(Vt + ((dr*64 + kc*32 + g*8) ^ ((dr & 7) << 3)));
        accO[df] = __builtin_amdgcn_mfma_f32_16x16x32_bf16(vf, pf, accO[df], 0, 0, 0);
      }
    }
  }
  const float inv = (lrun > 0.f) ? (1.f / lrun) : 0.f;  // row 0: lrun==0 -> zeros (start_mask)
  #pragma unroll
  for (int df = 0; df < 4; df++){
    #pragma unroll
    for (int r = 0; r < 4; r++){
      const int d = df*16 + g*4 + r;
      out[((size_t)b*512 + nh*64 + d)*1024 + qrow] = accO[df][r] * inv;
    }
  }
}

extern "C" void kernel_launch(void* const* d_in, const int* in_sizes, int n_in,
                              void* d_out, int out_size, void* d_ws, size_t ws_size,
                              hipStream_t stream)
{
  (void)in_sizes; (void)n_in; (void)out_size; (void)ws_size;
  const float* query = (const float*)d_in[0];
  const float* key   = (const float*)d_in[1];
  const float* w1[3] = {(const float*)d_in[2],  (const float*)d_in[8],  (const float*)d_in[14]};
  const float* b1[3] = {(const float*)d_in[3],  (const float*)d_in[9],  (const float*)d_in[15]};
  const float* w2[3] = {(const float*)d_in[4],  (const float*)d_in[10], (const float*)d_in[16]};
  const float* b2[3] = {(const float*)d_in[5],  (const float*)d_in[11], (const float*)d_in[17]};
  const float* wn[3] = {(const float*)d_in[6],  (const float*)d_in[12], (const float*)d_in[18]};
  const float* bn[3] = {(const float*)d_in[7],  (const float*)d_in[13], (const float*)d_in[19]};

  char* ws = (char*)d_ws;
  short* wsW = (short*)(ws + OFF_W);
  short* exq = (short*)(ws + OFF_EXQ);
  short* exk = (short*)(ws + OFF_EXK);
  short* h1  = (short*)(ws + OFF_H1);
  short* gr  = (short*)(ws + OFF_GR);
  short* tok = (short*)(ws + OFF_TOK);
  float* out = (float*)d_out;

  k_prep<<<dim3(960), dim3(256), 0, stream>>>(w1[0], w2[0], wn[0],
                                              w1[1], w2[1], wn[1],
                                              w1[2], w2[2], wn[2], wsW);
  k_elutr<<<dim3(16, 4, 16), dim3(256), 0, stream>>>(query, key, exq, exk);
  k_gemm1<<<dim3(4, 64, 3), dim3(256), 0, stream>>>(wsW, exq, exk, b1[0], b1[1], b1[2], h1);
  k_gemm2<<<dim3(4, 64, 3), dim3(256), 0, stream>>>(wsW, h1, b2[0], b2[1], b2[2], query, key, gr);
  k_gemm3<<<dim3(8, 64, 3), dim3(256), 0, stream>>>(wsW, gr, bn[0], bn[1], bn[2], tok);
  k_attn<<<dim3(16, 8, 8), dim3(256), 0, stream>>>(tok, out);
}

// Round 2
// 102.128 us; speedup vs baseline: 1.1706x; 1.1706x over previous
//
#include <hip/hip_runtime.h>
#include <cstdint>
#include <cstddef>

typedef __attribute__((ext_vector_type(4))) float f32x4;
typedef __attribute__((ext_vector_type(8))) short bf16x8;
typedef __attribute__((ext_vector_type(4))) short bf16x4;
typedef __attribute__((ext_vector_type(2))) short bf16x2;

#define DEVI static __device__ __forceinline__

DEVI short f2bf(float f){
  union { float f; uint32_t u; } v; v.f = f;
  uint32_t r = v.u + 0x7FFFu + ((v.u >> 16) & 1u);
  return (short)(r >> 16);
}
DEVI float bf2f(short h){
  union { uint32_t u; float f; } v; v.u = ((uint32_t)(uint16_t)h) << 16;
  return v.f;
}
DEVI float eluf(float x){ return x > 0.f ? x : (__expf(x) - 1.f); }
DEVI float sigm(float x){ return 1.f / (1.f + __expf(-x)); }

static constexpr int NPIX = 8 * 1024;   // B*S pixels

// ---- workspace layout (bytes), total ~58 MB ----
static constexpr size_t SZ_W   = (size_t)983040 * 2;        // 3 branches x (w1 65536 + w2 131072 + wn 131072) bf16
static constexpr size_t SZ_ACT = (size_t)NPIX * 256 * 2;    // 4 MiB bf16 activation
static constexpr size_t SZ_TOK = (size_t)NPIX * 512 * 2;    // 8 MiB bf16
static constexpr size_t OFF_W   = 0;
static constexpr size_t OFF_EXQ = OFF_W + SZ_W;
static constexpr size_t OFF_EXK = OFF_EXQ + SZ_ACT;
static constexpr size_t OFF_H1  = OFF_EXK + SZ_ACT;         // x3 branches
static constexpr size_t OFF_GR  = OFF_H1 + 3*SZ_ACT;        // x3 branches
static constexpr size_t OFF_TOK = OFF_GR + 3*SZ_ACT;        // x3 branches (channel-major bf16)

// ---------------- weight fp32 -> bf16 ----------------
__global__ void k_prep(const float* __restrict__ w1q, const float* __restrict__ w2q, const float* __restrict__ wnq,
                       const float* __restrict__ w1k, const float* __restrict__ w2k, const float* __restrict__ wnk,
                       const float* __restrict__ w1v, const float* __restrict__ w2v, const float* __restrict__ wnv,
                       short* __restrict__ dst)
{
  const float* s1[3] = {w1q, w1k, w1v};
  const float* s2[3] = {w2q, w2k, w2v};
  const float* s3[3] = {wnq, wnk, wnv};
  const int stride = gridDim.x * blockDim.x;
  for (int i = blockIdx.x * blockDim.x + threadIdx.x; i < 983040; i += stride){
    int br = i / 327680;
    int r  = i - br * 327680;
    float v;
    if (r < 65536)        v = s1[br][r];
    else if (r < 196608)  v = s2[br][r - 65536];
    else                  v = s3[br][r - 196608];
    dst[i] = f2bf(v);
  }
}

// ------------- elu + transpose to token-major bf16 -------------
// in: (B,256,1024) fp32 channel-major; out: (B*S, 256) bf16 token-major
__global__ void k_elutr(const float* __restrict__ qin, const float* __restrict__ kin,
                        short* __restrict__ exq, short* __restrict__ exk)
{
  const int z = blockIdx.z;
  const int which = z >> 3, b = z & 7;
  const float* x = which ? kin : qin;
  short* dst = which ? exk : exq;
  const int c0 = blockIdx.y * 64, s0 = blockIdx.x * 64;
  __shared__ short t[64][65];
  const int tid = threadIdx.x;
  for (int i = tid; i < 64*64; i += 256){
    int c = i >> 6, s = i & 63;
    float v = x[((size_t)b*256 + c0 + c)*1024 + s0 + s];
    t[s][c] = f2bf(eluf(v));
  }
  __syncthreads();
  for (int i = tid; i < 64*64; i += 256){
    int s = i >> 6, c = i & 63;
    dst[((size_t)(b*1024 + s0 + s))*256 + c0 + c] = t[s][c];
  }
}

// ---------------- GEMM core ----------------
// C tile = W[m0 .. m0+NA*64 rows (second 64 at +256)] @ act^T, cols nbase..nbase+127
// W row-major [M][256] bf16; act token-major [NPIX][256] bf16.
template<int NA>
DEVI void gemm_core(const short* __restrict__ Wt, const short* __restrict__ act,
                    int m0, int nbase, short* ldsA, short* ldsB,
                    f32x4 (&acc)[NA][4][2])
{
  const int tid = threadIdx.x;
  const int w = tid >> 6, g = (tid >> 4) & 3, li = tid & 15;
  for (int kb = 0; kb < 256; kb += 64){
    __syncthreads();
    #pragma unroll
    for (int it = 0; it < NA*2; it++){
      int i = tid + it*256;
      int m = i >> 3, kc = i & 7;
      int mr = (m & 63) + ((m >> 6) << 8);   // second A-tile rows at +256
      bf16x8 v = *(const bf16x8*)(Wt + (size_t)(m0 + mr)*256 + kb + kc*8);
      *(bf16x8*)(ldsA + ((m*64 + kc*8) ^ ((m & 7) << 3))) = v;
    }
    #pragma unroll
    for (int it = 0; it < 4; it++){
      int i = tid + it*256;
      int n = i >> 3, kc = i & 7;
      bf16x8 v = *(const bf16x8*)(act + (size_t)(nbase + n)*256 + kb + kc*8);
      *(bf16x8*)(ldsB + ((n*64 + kc*8) ^ ((n & 7) << 3))) = v;
    }
    __syncthreads();
    #pragma unroll
    for (int kk = 0; kk < 2; kk++){
      bf16x8 bfr[2];
      #pragma unroll
      for (int nt = 0; nt < 2; nt++){
        int n = w*32 + nt*16 + li;
        bfr[nt] = *(const bf16x8*)(ldsB + ((n*64 + kk*32 + g*8) ^ ((n & 7) << 3)));
      }
      #pragma unroll
      for (int a = 0; a < NA; a++){
        #pragma unroll
        for (int mt = 0; mt < 4; mt++){
          int m = a*64 + mt*16 + li;
          bf16x8 afr = *(const bf16x8*)(ldsA + ((m*64 + kk*32 + g*8) ^ ((m & 7) << 3)));
          #pragma unroll
          for (int nt = 0; nt < 2; nt++)
            acc[a][mt][nt] = __builtin_amdgcn_mfma_f32_16x16x32_bf16(afr, bfr[nt], acc[a][mt][nt], 0, 0, 0);
        }
      }
    }
  }
}

// gemm1: H1e = elu(W1 @ Ex + b1), token-major bf16 out
__global__ void k_gemm1(const short* __restrict__ wsW,
                        const short* __restrict__ exq, const short* __restrict__ exk,
                        const float* __restrict__ bq, const float* __restrict__ bk, const float* __restrict__ bv,
                        short* __restrict__ h1)
{
  __shared__ short ldsA[64*64];
  __shared__ short ldsB[128*64];
  const int z = blockIdx.z;
  const short* Wt  = wsW + (size_t)z * 327680;
  const short* act = (z == 0) ? exq : exk;
  const float* bias = (z == 0) ? bq : ((z == 1) ? bk : bv);
  short* out = h1 + (size_t)z * NPIX * 256;
  const int m0 = blockIdx.x * 64, nbase = blockIdx.y * 128;
  f32x4 acc[1][4][2] = {};
  gemm_core<1>(Wt, act, m0, nbase, ldsA, ldsB, acc);
  const int tid = threadIdx.x, w = tid >> 6, g = (tid >> 4) & 3, li = tid & 15;
  #pragma unroll
  for (int mt = 0; mt < 4; mt++){
    const int mb = m0 + mt*16 + g*4;
    #pragma unroll
    for (int nt = 0; nt < 2; nt++){
      const int n = nbase + w*32 + nt*16 + li;
      bf16x4 pk;
      #pragma unroll
      for (int r = 0; r < 4; r++)
        pk[r] = f2bf(eluf(acc[0][mt][nt][r] + bias[mb + r]));
      *(bf16x4*)(out + (size_t)n*256 + mb) = pk;
    }
  }
}

// gemm2: [a;g] = W2 @ H1e + b2 ; GR = X + a*sigmoid(g), token-major bf16 out
__global__ void k_gemm2(const short* __restrict__ wsW, const short* __restrict__ h1,
                        const float* __restrict__ bq, const float* __restrict__ bk, const float* __restrict__ bv,
                        const float* __restrict__ xq, const float* __restrict__ xk,
                        short* __restrict__ grb)
{
  __shared__ short ldsA[128*64];
  __shared__ short ldsB[128*64];
  const int z = blockIdx.z;
  const short* Wt  = wsW + (size_t)z * 327680 + 65536;
  const short* act = h1 + (size_t)z * NPIX * 256;
  const float* bias = (z == 0) ? bq : ((z == 1) ? bk : bv);
  const float* X = (z == 0) ? xq : xk;
  short* out = grb + (size_t)z * NPIX * 256;
  const int m0 = blockIdx.x * 64, nbase = blockIdx.y * 128;
  f32x4 acc[2][4][2] = {};
  gemm_core<2>(Wt, act, m0, nbase, ldsA, ldsB, acc);
  const int tid = threadIdx.x, w = tid >> 6, g = (tid >> 4) & 3, li = tid & 15;
  #pragma unroll
  for (int mt = 0; mt < 4; mt++){
    const int mb = m0 + mt*16 + g*4;
    #pragma unroll
    for (int nt = 0; nt < 2; nt++){
      const int n = nbase + w*32 + nt*16 + li;
      const int bidx = n >> 10, sp = n & 1023;
      bf16x4 pk;
      #pragma unroll
      for (int r = 0; r < 4; r++){
        const int m = mb + r;
        float a  = acc[0][mt][nt][r] + bias[m];
        float gg = acc[1][mt][nt][r] + bias[m + 256];
        float xv = X[((size_t)bidx*256 + m)*1024 + sp];
        pk[r] = f2bf(xv + a * sigm(gg));
      }
      *(bf16x4*)(out + (size_t)n*256 + mb) = pk;
    }
  }
}

// gemm3: tok = Wn @ GR + bn, stored CHANNEL-major (B,512,1024) bf16 (= attention token rows)
__global__ void k_gemm3(const short* __restrict__ wsW, const short* __restrict__ grb,
                        const float* __restrict__ bq, const float* __restrict__ bk, const float* __restrict__ bv,
                        short* __restrict__ tok)
{
  __shared__ short ldsA[64*64];
  __shared__ short ldsB[128*64];
  const int z = blockIdx.z;
  const short* Wt  = wsW + (size_t)z * 327680 + 196608;
  const short* act = grb + (size_t)z * NPIX * 256;
  const float* bias = (z == 0) ? bq : ((z == 1) ? bk : bv);
  short* out = tok + (size_t)z * NPIX * 512;
  const int m0 = blockIdx.x * 64, nbase = blockIdx.y * 128;
  f32x4 acc[1][4][2] = {};
  gemm_core<1>(Wt, act, m0, nbase, ldsA, ldsB, acc);
  const int tid = threadIdx.x, w = tid >> 6, g = (tid >> 4) & 3, li = tid & 15;
  #pragma unroll
  for (int mt = 0; mt < 4; mt++){
    #pragma unroll
    for (int nt = 0; nt < 2; nt++){
      const int n = nbase + w*32 + nt*16 + li;
      const int bidx = n >> 10, sp = n & 1023;
      #pragma unroll
      for (int r = 0; r < 4; r++){
        const int m = m0 + mt*16 + g*4 + r;
        out[((size_t)bidx*512 + m)*1024 + sp] = f2bf(acc[0][mt][nt][r] + bias[m]);
      }
    }
  }
}

// ---------------- flash attention ----------------
// tok viewed as (B*1024 tokens, 512 feat) bf16; per (b, head): Q,K,V (1024 x 64).
// Strict causal (key < query), scale 1/sqrt(512), row 0 -> 0.
// Swapped QK^T: S^T = mfma(K, Q^T) so softmax state is lane-local (lane owns q = lane&15).
//
// Grid = 1024 flat blocks. qt is chosen via a permutation such that every
// stride-256 block family {i, i+256, i+512, i+768} (what one CU receives under
// XCD round-robin dispatch) has equal total work: perm stride-4 subsets all sum
// to 30 -> 34 flash iterations per CU, vs up to 64 with the naive qt=i%16 map.
__global__ void k_attn(const short* __restrict__ tok, float* __restrict__ out)
{
  const short* qtok = tok;
  const short* ktok = tok + (size_t)NPIX * 512;
  const short* vtok = tok + (size_t)2 * NPIX * 512;
  const int flat = blockIdx.x;
  const int p = flat >> 6;
  const int g4 = p >> 2, r4 = p & 3;
  // perm = [15,14,13,12, 0,1,2,3, 11,10,9,8, 4,5,6,7]
  const int qt = (g4 == 0) ? (15 - r4) : (g4 == 1) ? r4 : (g4 == 2) ? (11 - r4) : (4 + r4);
  const int bh = flat & 63;
  const int b = bh >> 3, nh = bh & 7;
  const int tid = threadIdx.x, lane = tid & 63, w = tid >> 6, g = (tid >> 4) & 3, li = tid & 15;
  const int qbase = qt * 64;
  const int qrow = qbase + w*16 + li;       // this lane's query token
  __shared__ short Kl[64*64];
  __shared__ short Vt[64*64];               // V transposed: [d][k]
  __shared__ short Pl[4][1024];             // per-wave P [16 q][64 k]

  const short* qptr = qtok + ((size_t)(b*1024 + qrow))*512 + nh*64;
  bf16x8 qf0 = *(const bf16x8*)(qptr + g*8);
  bf16x8 qf1 = *(const bf16x8*)(qptr + 32 + g*8);

  f32x4 accO[4] = {};                       // O^T: 4 d-frags x (16d x 16q)
  float mrun = -1e30f, lrun = 0.f;
  const float scale = 0.04419417382415922f; // 1/sqrt(512)
  short* Pw = &Pl[w][0];

  for (int kt = 0; kt <= qt; kt++){
    const int kb = kt * 64;
    __syncthreads();
    #pragma unroll
    for (int it = 0; it < 2; it++){
      int i = tid + it*256;
      int kr = i >> 3, kc = i & 7;
      bf16x8 v = *(const bf16x8*)(ktok + ((size_t)(b*1024 + kb + kr))*512 + nh*64 + kc*8);
      *(bf16x8*)(Kl + ((kr*64 + kc*8) ^ ((kr & 7) << 3))) = v;
    }
    #pragma unroll
    for (int it = 0; it < 2; it++){
      int d0 = w*8 + it*32;                 // d uniform within wave -> conflict-free writes
      bf16x8 v = *(const bf16x8*)(vtok + ((size_t)(b*1024 + kb + lane))*512 + nh*64 + d0);
      #pragma unroll
      for (int j = 0; j < 8; j++){
        int d = d0 + j;
        Vt[(d*64 + lane) ^ ((d & 7) << 3)] = v[j];
      }
    }
    __syncthreads();

    // S^T frags: 4 x (16 keys x 16 q)
    float pv[16];
    float mt_ = -1e30f;
    const bool diag = (kt == qt);
    #pragma unroll
    for (int kf = 0; kf < 4; kf++){
      f32x4 sa = {};
      const int krow = kf*16 + li;
      bf16x8 ka = *(const bf16x8*)(Kl + ((krow*64 + g*8) ^ ((krow & 7) << 3)));
      bf16x8 kbf = *(const bf16x8*)(Kl + ((krow*64 + 32 + g*8) ^ ((krow & 7) << 3)));
      sa = __builtin_amdgcn_mfma_f32_16x16x32_bf16(ka, qf0, sa, 0, 0, 0);
      sa = __builtin_amdgcn_mfma_f32_16x16x32_bf16(kbf, qf1, sa, 0, 0, 0);
      #pragma unroll
      for (int r = 0; r < 4; r++){
        const int keyg = kb + kf*16 + g*4 + r;
        float s = sa[r] * scale;
        const bool ok = (!diag) || (keyg < qrow);   // strict causal
        s = ok ? s : -1e30f;
        pv[kf*4 + r] = s;
        mt_ = fmaxf(mt_, s);
      }
    }
    mt_ = fmaxf(mt_, __shfl_xor(mt_, 16));
    mt_ = fmaxf(mt_, __shfl_xor(mt_, 32));
    const float mnew = fmaxf(mrun, mt_);
    const float alpha = __expf(mrun - mnew);
    short pr[16];
    float rs = 0.f;
    #pragma unroll
    for (int i2 = 0; i2 < 16; i2++){
      float p2 = (pv[i2] > -9e29f) ? __expf(pv[i2] - mnew) : 0.f;
      short pb = f2bf(p2);
      pr[i2] = pb;
      rs += bf2f(pb);            // denominator from rounded P (consistent with numerator)
    }
    rs += __shfl_xor(rs, 16);
    rs += __shfl_xor(rs, 32);
    lrun = lrun * alpha + rs;
    mrun = mnew;
    #pragma unroll
    for (int df = 0; df < 4; df++){
      accO[df][0] *= alpha; accO[df][1] *= alpha;
      accO[df][2] *= alpha; accO[df][3] *= alpha;
    }
    // P rows to per-wave LDS (b32 packed pairs; keys 4g+2rp consecutive)
    #pragma unroll
    for (int kf = 0; kf < 4; kf++){
      #pragma unroll
      for (int rp = 0; rp < 2; rp++){
        bf16x2 two;
        two[0] = pr[kf*4 + rp*2];
        two[1] = pr[kf*4 + rp*2 + 1];
        const int key = kf*16 + g*4 + rp*2;
        *(bf16x2*)(Pw + ((li*64 + key) ^ ((li & 7) << 3))) = two;
      }
    }
    // O^T += V^T @ P^T
    #pragma unroll
    for (int kc = 0; kc < 2; kc++){
      bf16x8 pf = *(const bf16x8*)(Pw + ((li*64 + kc*32 + g*8) ^ ((li & 7) << 3)));
      #pragma unroll
      for (int df = 0; df < 4; df++){
        const int dr = df*16 + li;
        bf16x8 vf = *(const bf16x8*)(Vt + ((dr*64 + kc*32 + g*8) ^ ((dr & 7) << 3)));
        accO[df] = __builtin_amdgcn_mfma_f32_16x16x32_bf16(vf, pf, accO[df], 0, 0, 0);
      }
    }
  }
  const float inv = (lrun > 0.f) ? (1.f / lrun) : 0.f;  // row 0: lrun==0 -> zeros (start_mask)
  #pragma unroll
  for (int df = 0; df < 4; df++){
    #pragma unroll
    for (int r = 0; r < 4; r++){
      const int d = df*16 + g*4 + r;
      out[((size_t)b*512 + nh*64 + d)*1024 + qrow] = accO[df][r] * inv;
    }
  }
}

extern "C" void kernel_launch(void* const* d_in, const int* in_sizes, int n_in,
                              void* d_out, int out_size, void* d_ws, size_t ws_size,
                              hipStream_t stream)
{
  (void)in_sizes; (void)n_in; (void)out_size; (void)ws_size;
  const float* query = (const float*)d_in[0];
  const float* key   = (const float*)d_in[1];
  const float* w1[3] = {(const float*)d_in[2],  (const float*)d_in[8],  (const float*)d_in[14]};
  const float* b1[3] = {(const float*)d_in[3],  (const float*)d_in[9],  (const float*)d_in[15]};
  const float* w2[3] = {(const float*)d_in[4],  (const float*)d_in[10], (const float*)d_in[16]};
  const float* b2[3] = {(const float*)d_in[5],  (const float*)d_in[11], (const float*)d_in[17]};
  const float* wn[3] = {(const float*)d_in[6],  (const float*)d_in[12], (const float*)d_in[18]};
  const float* bn[3] = {(const float*)d_in[7],  (const float*)d_in[13], (const float*)d_in[19]};

  char* ws = (char*)d_ws;
  short* wsW = (short*)(ws + OFF_W);
  short* exq = (short*)(ws + OFF_EXQ);
  short* exk = (short*)(ws + OFF_EXK);
  short* h1  = (short*)(ws + OFF_H1);
  short* gr  = (short*)(ws + OFF_GR);
  short* tok = (short*)(ws + OFF_TOK);
  float* out = (float*)d_out;

  k_prep<<<dim3(960), dim3(256), 0, stream>>>(w1[0], w2[0], wn[0],
                                              w1[1], w2[1], wn[1],
                                              w1[2], w2[2], wn[2], wsW);
  k_elutr<<<dim3(16, 4, 16), dim3(256), 0, stream>>>(query, key, exq, exk);
  k_gemm1<<<dim3(4, 64, 3), dim3(256), 0, stream>>>(wsW, exq, exk, b1[0], b1[1], b1[2], h1);
  k_gemm2<<<dim3(4, 64, 3), dim3(256), 0, stream>>>(wsW, h1, b2[0], b2[1], b2[2], query, key, gr);
  k_gemm3<<<dim3(8, 64, 3), dim3(256), 0, stream>>>(wsW, gr, bn[0], bn[1], bn[2], tok);
  k_attn<<<dim3(1024), dim3(256), 0, stream>>>(tok, out);
}